// Round 1
// baseline (75.320 us; speedup 1.0000x reference)
//
#include <hip/hip_runtime.h>
#include <hip/hip_bf16.h>

#define B_ 2
#define S_ 1024
#define E_ 128
#define H_ 4
#define D_ 32
#define BHSD (B_ * H_ * S_ * D_)   // 262144 floats per tensor

// ---------------------------------------------------------------------------
// Kernel A: fused QKV projection.
//   q/k/v[e] = sum_c x[row][c] * W[e][c] + b[e], written in (B,H,S,D) layout.
// grid = (row_tiles=256, mat=3), block = 128 threads (thread = output col e).
// Each block handles 8 rows; x rows staged in LDS; W rows read via L2 (256 KB
// total weights — L2-resident across all blocks).
// ---------------------------------------------------------------------------
__global__ __launch_bounds__(128) void qkv_kernel(
    const float* __restrict__ x,
    const float* __restrict__ Wq, const float* __restrict__ bq,
    const float* __restrict__ Wk, const float* __restrict__ bk,
    const float* __restrict__ Wv, const float* __restrict__ bv,
    float* __restrict__ ws) {
  const int mat = blockIdx.y;
  const float* W    = (mat == 0) ? Wq : (mat == 1) ? Wk : Wv;
  const float* bias = (mat == 0) ? bq : (mat == 1) ? bk : bv;
  float* outbase = ws + (size_t)mat * BHSD;

  const int row0 = blockIdx.x * 8;
  const int t = threadIdx.x;

  __shared__ __align__(16) float xs[8 * E_];
  const float4* xg = (const float4*)(x + (size_t)row0 * E_);
  float4* xs4 = (float4*)xs;
  #pragma unroll
  for (int i = 0; i < 2; ++i) xs4[t + i * 128] = xg[t + i * 128];
  __syncthreads();

  const int col = t;                       // output feature e in [0,128)
  const float4* W4 = (const float4*)(W + (size_t)col * E_);

  float acc[8];
  #pragma unroll
  for (int r = 0; r < 8; ++r) acc[r] = 0.f;

  #pragma unroll 4
  for (int c4 = 0; c4 < E_ / 4; ++c4) {
    float4 w = W4[c4];
    #pragma unroll
    for (int r = 0; r < 8; ++r) {
      float4 xv = xs4[r * (E_ / 4) + c4];
      acc[r] += xv.x * w.x + xv.y * w.y + xv.z * w.z + xv.w * w.w;
    }
  }

  const float bcol = bias[col];
  const int h = col >> 5, d = col & 31;
  #pragma unroll
  for (int r = 0; r < 8; ++r) {
    int row = row0 + r;                    // flat row over B*S
    int b = row >> 10, s = row & 1023;
    outbase[(((size_t)(b * H_ + h)) * S_ + s) * D_ + d] = acc[r] + bcol;
  }
}

// ---------------------------------------------------------------------------
// Kernel B: fused ultrametric (Chebyshev) flash attention.
//   dist[i][j] = max_d |q[i][d] - k[j][d]|;  attn = softmax(-dist);  O = attn@V
// Online softmax tracks running MIN distance m:  p = exp(m - dist).
// grid = (S/QT=64, B*H=8), block = 256 (il = t>>4 row-in-tile, jg = t&15).
// K/V tiles (64 rows) staged in LDS with row stride 36 floats (16B aligned,
// conflict-friendly). Q row held in registers (32 VGPR).
// ---------------------------------------------------------------------------
#define QT 16
#define KT 64
#define NJ 4          // keys per thread per tile = KT*QT/256
#define LDSTRIDE 36   // floats per LDS row (144 B)

__global__ __launch_bounds__(256) void attn_kernel(float* __restrict__ ws) {
  const float* qg = ws + (size_t)blockIdx.y * S_ * D_;
  const float* kg = ws + BHSD + (size_t)blockIdx.y * S_ * D_;
  const float* vg = ws + 2 * BHSD + (size_t)blockIdx.y * S_ * D_;
  float* att = ws + 3 * (size_t)BHSD;

  __shared__ __align__(16) float ks[KT * LDSTRIDE];
  __shared__ __align__(16) float vs[KT * LDSTRIDE];

  const int t = threadIdx.x;
  const int il = t >> 4;        // 0..15 : row within Q tile
  const int jg = t & 15;        // 0..15 : key-group lane
  const int qrow = blockIdx.x * QT + il;

  // Q row -> registers (lanes in a 16-lane group read same addrs: broadcast)
  float4 q4[8];
  const float4* qr = (const float4*)(qg + (size_t)qrow * D_);
  #pragma unroll
  for (int i = 0; i < 8; ++i) q4[i] = qr[i];

  float m = 1e30f;   // running min distance
  float l = 0.f;     // running denom (partial over this lane's keys)
  float o[32];
  #pragma unroll
  for (int d = 0; d < 32; ++d) o[d] = 0.f;

  for (int kt = 0; kt < S_ / KT; ++kt) {
    // ---- stage K/V tile: 512 float4 each, 2 per thread, coalesced ----
    const float4* kgt = (const float4*)(kg + (size_t)kt * KT * D_);
    const float4* vgt = (const float4*)(vg + (size_t)kt * KT * D_);
    #pragma unroll
    for (int q_ = 0; q_ < 2; ++q_) {
      int f = q_ * 256 + t;               // 0..511
      int row = f >> 3, c4 = f & 7;
      *(float4*)(ks + row * LDSTRIDE + c4 * 4) = kgt[f];
      *(float4*)(vs + row * LDSTRIDE + c4 * 4) = vgt[f];
    }
    __syncthreads();

    // ---- Chebyshev distances for my NJ keys ----
    float p[NJ];
    float tmin = 1e30f;
    #pragma unroll
    for (int jj = 0; jj < NJ; ++jj) {
      const int j = jg + 16 * jj;
      const float4* kr = (const float4*)(ks + j * LDSTRIDE);
      float d0 = 0.f, d1 = 0.f, d2 = 0.f, d3 = 0.f;
      #pragma unroll
      for (int c4 = 0; c4 < 8; ++c4) {
        float4 kv = kr[c4];
        d0 = fmaxf(d0, fabsf(q4[c4].x - kv.x));
        d1 = fmaxf(d1, fabsf(q4[c4].y - kv.y));
        d2 = fmaxf(d2, fabsf(q4[c4].z - kv.z));
        d3 = fmaxf(d3, fabsf(q4[c4].w - kv.w));
      }
      float dm = fmaxf(fmaxf(d0, d1), fmaxf(d2, d3));
      p[jj] = dm;
      tmin = fminf(tmin, dm);
    }
    // min over the 16 lanes sharing this Q row
    #pragma unroll
    for (int off = 1; off < 16; off <<= 1)
      tmin = fminf(tmin, __shfl_xor(tmin, off));

    const float mnew = fminf(m, tmin);
    const float scale = __expf(mnew - m);   // <=1; first tile: exp(-1e30)=0
    l *= scale;
    #pragma unroll
    for (int d = 0; d < 32; ++d) o[d] *= scale;
    m = mnew;

    #pragma unroll
    for (int jj = 0; jj < NJ; ++jj) {
      float pj = __expf(m - p[jj]);
      p[jj] = pj;
      l += pj;
    }

    // ---- O += P @ V ----
    #pragma unroll
    for (int jj = 0; jj < NJ; ++jj) {
      const int j = jg + 16 * jj;
      const float4* vr = (const float4*)(vs + j * LDSTRIDE);
      #pragma unroll
      for (int c4 = 0; c4 < 8; ++c4) {
        float4 vv = vr[c4];
        o[c4 * 4 + 0] += p[jj] * vv.x;
        o[c4 * 4 + 1] += p[jj] * vv.y;
        o[c4 * 4 + 2] += p[jj] * vv.z;
        o[c4 * 4 + 3] += p[jj] * vv.w;
      }
    }
    __syncthreads();
  }

  // ---- reduce over the 16 lanes of this Q row (butterfly: all lanes total)
  #pragma unroll
  for (int off = 1; off < 16; off <<= 1) {
    l += __shfl_xor(l, off);
    #pragma unroll
    for (int d = 0; d < 32; ++d) o[d] += __shfl_xor(o[d], off);
  }

  const float inv = 1.0f / l;
  // write attended back in (B,S,E) layout: e = h*32 + d ; lane jg owns 2 d's
  const int b = blockIdx.y >> 2, h = blockIdx.y & 3;
  const size_t row = (size_t)b * S_ + qrow;
  float2 w2;
  w2.x = o[jg * 2 + 0] * inv;
  w2.y = o[jg * 2 + 1] * inv;
  *(float2*)(att + row * E_ + h * D_ + jg * 2) = w2;
}

// ---------------------------------------------------------------------------
// Kernel C: output projection  out = att @ Wo^T + bo   (same shape as A)
// grid = 256, block = 128.
// ---------------------------------------------------------------------------
__global__ __launch_bounds__(128) void out_kernel(
    const float* __restrict__ att,
    const float* __restrict__ Wo, const float* __restrict__ bo,
    float* __restrict__ out) {
  const int row0 = blockIdx.x * 8;
  const int t = threadIdx.x;

  __shared__ __align__(16) float xs[8 * E_];
  const float4* xg = (const float4*)(att + (size_t)row0 * E_);
  float4* xs4 = (float4*)xs;
  #pragma unroll
  for (int i = 0; i < 2; ++i) xs4[t + i * 128] = xg[t + i * 128];
  __syncthreads();

  const int col = t;
  const float4* W4 = (const float4*)(Wo + (size_t)col * E_);

  float acc[8];
  #pragma unroll
  for (int r = 0; r < 8; ++r) acc[r] = 0.f;

  #pragma unroll 4
  for (int c4 = 0; c4 < E_ / 4; ++c4) {
    float4 w = W4[c4];
    #pragma unroll
    for (int r = 0; r < 8; ++r) {
      float4 xv = xs4[r * (E_ / 4) + c4];
      acc[r] += xv.x * w.x + xv.y * w.y + xv.z * w.z + xv.w * w.w;
    }
  }

  const float bcol = bo[col];
  #pragma unroll
  for (int r = 0; r < 8; ++r)
    out[(size_t)(row0 + r) * E_ + col] = acc[r] + bcol;
}

// ---------------------------------------------------------------------------
extern "C" void kernel_launch(void* const* d_in, const int* in_sizes, int n_in,
                              void* d_out, int out_size, void* d_ws, size_t ws_size,
                              hipStream_t stream) {
  const float* x  = (const float*)d_in[0];
  const float* Wq = (const float*)d_in[1];
  const float* bq = (const float*)d_in[2];
  const float* Wk = (const float*)d_in[3];
  const float* bk = (const float*)d_in[4];
  const float* Wv = (const float*)d_in[5];
  const float* bv = (const float*)d_in[6];
  const float* Wo = (const float*)d_in[7];
  const float* bo = (const float*)d_in[8];
  float* ws  = (float*)d_ws;
  float* out = (float*)d_out;

  // ws layout (floats): [0,BHSD) q | [BHSD,2B) k | [2B,3B) v | [3B,4B) att
  qkv_kernel<<<dim3((B_ * S_) / 8, 3), 128, 0, stream>>>(x, Wq, bq, Wk, bk, Wv, bv, ws);
  attn_kernel<<<dim3(S_ / QT, B_ * H_), 256, 0, stream>>>(ws);
  out_kernel<<<dim3((B_ * S_) / 8), 128, 0, stream>>>(ws + 3 * (size_t)BHSD, Wo, bo, out);
}